// Round 4
// baseline (883.339 us; speedup 1.0000x reference)
//
#include <hip/hip_runtime.h>
#include <hip/hip_bf16.h>
#include <math.h>

// ---------------------------------------------------------------------------
// Types
// ---------------------------------------------------------------------------
typedef short v8s __attribute__((ext_vector_type(8)));   // 8 x bf16 bits (4 VGPR)
typedef float v4f __attribute__((ext_vector_type(4)));   // MFMA accumulator

__device__ __forceinline__ unsigned short f2bf(float f) {
  union { float f; unsigned u; } a; a.f = f;
  unsigned u = a.u + 0x7fffu + ((a.u >> 16) & 1u);   // RNE
  return (unsigned short)(u >> 16);
}

// async global->LDS, 16 B per lane; LDS dest = wave-uniform base + lane*16
__device__ __forceinline__ void gld_lds16(const unsigned short* g, unsigned short* l) {
  __builtin_amdgcn_global_load_lds(
      (const __attribute__((address_space(1))) void*)g,
      (__attribute__((address_space(3))) void*)l,
      16, 0, 0);
}

// ---------------------------------------------------------------------------
// fp32 -> bf16 (same layout), vectorized x4
// ---------------------------------------------------------------------------
__global__ void cvt_f32_bf16(const float* __restrict__ in,
                             unsigned short* __restrict__ out, int n4) {
  int i = blockIdx.x * blockDim.x + threadIdx.x;
  if (i >= n4) return;
  float4 v = reinterpret_cast<const float4*>(in)[i];
  ushort4 o;
  o.x = f2bf(v.x); o.y = f2bf(v.y); o.z = f2bf(v.z); o.w = f2bf(v.w);
  reinterpret_cast<ushort4*>(out)[i] = o;
}

// ---------------------------------------------------------------------------
// fp32 [K,N] -> bf16 [N,K] transpose-convert (weights). block (32,8)
// ---------------------------------------------------------------------------
__global__ void cvt_transpose(const float* __restrict__ in,
                              unsigned short* __restrict__ out, int K, int N) {
  __shared__ float t[32][33];
  int bx = blockIdx.x, by = blockIdx.y;
  int tx = threadIdx.x, ty = threadIdx.y;
#pragma unroll
  for (int i = 0; i < 4; i++) {
    int k = by * 32 + ty + i * 8;
    t[ty + i * 8][tx] = in[(size_t)k * N + bx * 32 + tx];
  }
  __syncthreads();
#pragma unroll
  for (int i = 0; i < 4; i++) {
    int n = bx * 32 + ty + i * 8;
    out[(size_t)n * K + by * 32 + tx] = f2bf(t[tx][ty + i * 8]);
  }
}

// ---------------------------------------------------------------------------
// bf16 MFMA GEMM: C[M,N] = act(A[M,K] @ B[K,N] + bias)
// A row-major bf16, BT = B^T row-major [N,K] bf16.
// 256 threads = 4 waves, tile 128x128, BK=32 DOUBLE-BUFFERED (2x8KB x2 arrays
// = 32 KB LDS), each wave 64x64 (4x4 MFMA tiles).
// K-loop: barrier -> issue async loads for tile k+1 into the other buffer ->
// compute tile k. The vmcnt(0) drain the compiler emits before s_barrier then
// waits on loads issued one full compute phase earlier (prefetch distance 1),
// hiding L2 latency without relying on co-resident blocks.
// XOR swizzle f(r)=(r^(r>>2))&3 on the 4 16B-chunks per row keeps the frag
// ds_read_b128s at 2-way bank aliasing (free); realized by permuting the
// GLOBAL source chunk per lane (the DMA lane->LDS map is fixed).
// Ragged M: OOB rows read workspace garbage (mapped) and are discarded at store.
// N must be mult of 128, K mult of 32.
// ---------------------------------------------------------------------------
template<bool RELU, bool OUTF, bool OUTB>
__global__ __launch_bounds__(256)
void gemm_bf16(const unsigned short* __restrict__ A,
               const unsigned short* __restrict__ BT,
               const float* __restrict__ bias,
               float* __restrict__ Cf, unsigned short* __restrict__ Cb,
               int M, int N, int K) {
  __shared__ __align__(16) unsigned short lA[2][128 * 32];   // 2 x 8 KB
  __shared__ __align__(16) unsigned short lB[2][128 * 32];
  int tid  = threadIdx.x;
  int lane = tid & 63;
  int wave = tid >> 6;
  int wr = (wave >> 1) * 64;
  int wc = (wave & 1) * 64;
  int quad = lane >> 4;
  int l15  = lane & 15;
  int m0 = blockIdx.y * 128;
  int n0 = blockIdx.x * 128;

  // staging: row = tid>>2 (0..63, +64 for 2nd issue), physical chunk = tid&3,
  // global source chunk = (tid&3) ^ f(row&15)
  int srow = tid >> 2;
  int fsr  = (srow ^ (srow >> 2)) & 3;
  int sc   = ((tid & 3) ^ fsr) * 8;
  const unsigned short* gA = A  + (size_t)(m0 + srow) * K + sc;
  const unsigned short* gB = BT + (size_t)(n0 + srow) * K + sc;
  const size_t half = (size_t)64 * K;       // rows 64..127 of the tile
  // frag read: global chunk `quad` of row (..+l15) lives at physical chunk quad^f(l15)
  int fl = (l15 ^ (l15 >> 2)) & 3;
  int rc = (quad ^ fl) * 8;

  const v4f vzero = {0.f, 0.f, 0.f, 0.f};
  v4f acc[4][4];
#pragma unroll
  for (int i = 0; i < 4; i++)
#pragma unroll
    for (int j = 0; j < 4; j++) acc[i][j] = vzero;

  // prologue: issue tile 0 into buffer 0
  {
    unsigned short* dA = &lA[0][0] + wave * 512;
    unsigned short* dB = &lB[0][0] + wave * 512;
    gld_lds16(gA, dA);
    gld_lds16(gA + half, dA + 2048);
    gld_lds16(gB, dB);
    gld_lds16(gB + half, dB + 2048);
  }

  int nk = K >> 5;
  for (int kk = 0; kk < nk; kk++) {
    __syncthreads();          // tile kk ready (loads issued 1 phase ago); prev reads done
    if (kk + 1 < nk) {
      int k1 = (kk + 1) << 5;
      int b1 = (kk + 1) & 1;
      unsigned short* dA = &lA[b1][0] + wave * 512;
      unsigned short* dB = &lB[b1][0] + wave * 512;
      gld_lds16(gA + k1, dA);
      gld_lds16(gA + k1 + half, dA + 2048);
      gld_lds16(gB + k1, dB);
      gld_lds16(gB + k1 + half, dB + 2048);
    }
    int b = kk & 1;
    v8s aF[4], bF[4];
#pragma unroll
    for (int i = 0; i < 4; i++) aF[i] = *(const v8s*)&lA[b][(wr + i * 16 + l15) * 32 + rc];
#pragma unroll
    for (int j = 0; j < 4; j++) bF[j] = *(const v8s*)&lB[b][(wc + j * 16 + l15) * 32 + rc];
#pragma unroll
    for (int i = 0; i < 4; i++)
#pragma unroll
      for (int j = 0; j < 4; j++)
        acc[i][j] = __builtin_amdgcn_mfma_f32_16x16x32_bf16(aF[i], bF[j], acc[i][j], 0, 0, 0);
  }

  // epilogue: C/D layout col=lane&15, row=quad*4+reg
#pragma unroll
  for (int j = 0; j < 4; j++) {
    int col = n0 + wc + j * 16 + l15;
    float bv = bias ? bias[col] : 0.f;
#pragma unroll
    for (int i = 0; i < 4; i++) {
#pragma unroll
      for (int r = 0; r < 4; r++) {
        int row = m0 + wr + i * 16 + quad * 4 + r;
        if (row < M) {
          float v = acc[i][j][r] + bv;
          if (RELU) v = fmaxf(v, 0.f);
          if (OUTF) Cf[(size_t)row * N + col] = v;
          if (OUTB) Cb[(size_t)row * N + col] = f2bf(v);
        }
      }
    }
  }
}

// ---------------------------------------------------------------------------
// Flash-style MFMA attention. grid (Sq/64, H, B), 256 threads = 4 waves.
// One WG: 64 query rows of one (b,h); KV chunks of 64, online softmax.
// Q/K/V bf16 with row stride; O bf16 [B*Sq, H*64] head-merged.
// ---------------------------------------------------------------------------
__global__ __launch_bounds__(256)
void attn_kernel(const unsigned short* __restrict__ Q,
                 const unsigned short* __restrict__ K,
                 const unsigned short* __restrict__ V,
                 unsigned short* __restrict__ O,
                 int q_rowstride, int kv_rowstride, int o_rowstride,
                 int q_batch_rows, int kv_batch_rows, int Skv, float scale) {
  __shared__ __align__(16) unsigned short lK[64][72];      // [kv][d]
  __shared__ __align__(16) unsigned short lV[64][72];      // transposed: [d][kv]
  __shared__ __align__(16) unsigned short lP[4][16][72];   // per-wave P (A-layout src)
  int tid  = threadIdx.x;
  int lane = tid & 63;
  int wave = tid >> 6;
  int quad = lane >> 4;
  int l15  = lane & 15;
  int qt = blockIdx.x, h = blockIdx.y, b = blockIdx.z;

  const unsigned short* Qb = Q + (size_t)b * q_batch_rows * q_rowstride + h * 64;
  const unsigned short* Kb = K + (size_t)b * kv_batch_rows * kv_rowstride + h * 64;
  const unsigned short* Vb = V + (size_t)b * kv_batch_rows * kv_rowstride + h * 64;

  // Q A-frags (rows qt*64 + wave*16 + l15, k = c*32 + quad*8 + j)
  v8s qf0, qf1;
  {
    const unsigned short* qr = Qb + (size_t)(qt * 64 + wave * 16 + l15) * q_rowstride + quad * 8;
    qf0 = *(const v8s*)(qr);
    qf1 = *(const v8s*)(qr + 32);
  }

  const v4f vzero = {0.f, 0.f, 0.f, 0.f};
  v4f o_acc[4];
#pragma unroll
  for (int t = 0; t < 4; t++) o_acc[t] = vzero;
  float m_r[4], l_r[4];
#pragma unroll
  for (int r = 0; r < 4; r++) { m_r[r] = -1e30f; l_r[r] = 0.f; }

  int sr = tid >> 2;            // kv row in chunk 0..63
  int sc = (tid & 3) * 16;      // 0/16/32/48

  int nch = (Skv + 63) >> 6;
  for (int ch = 0; ch < nch; ch++) {
    int base = ch * 64;
    int gr = base + sr;
    v8s k0v = {}, k1v = {}, v0v = {}, v1v = {};
    if (gr < Skv) {
      const unsigned short* kp = Kb + (size_t)gr * kv_rowstride + sc;
      const unsigned short* vp = Vb + (size_t)gr * kv_rowstride + sc;
      k0v = *(const v8s*)kp;  k1v = *(const v8s*)(kp + 8);
      v0v = *(const v8s*)vp;  v1v = *(const v8s*)(vp + 8);
    }
    __syncthreads();            // prev chunk's lV/lP reads done
    *(v8s*)&lK[sr][sc]     = k0v;
    *(v8s*)&lK[sr][sc + 8] = k1v;
#pragma unroll
    for (int e = 0; e < 8; e++) {
      lV[sc + e][sr]     = (unsigned short)v0v[e];
      lV[sc + 8 + e][sr] = (unsigned short)v1v[e];
    }
    __syncthreads();

    // S = Q K^T for 4 kv sub-tiles of 16
    float s[4][4];
#pragma unroll
    for (int t = 0; t < 4; t++) {
      v8s kf0 = *(const v8s*)&lK[t * 16 + l15][quad * 8];
      v8s kf1 = *(const v8s*)&lK[t * 16 + l15][32 + quad * 8];
      v4f sacc = vzero;
      sacc = __builtin_amdgcn_mfma_f32_16x16x32_bf16(qf0, kf0, sacc, 0, 0, 0);
      sacc = __builtin_amdgcn_mfma_f32_16x16x32_bf16(qf1, kf1, sacc, 0, 0, 0);
      int kvpos = base + t * 16 + l15;     // C-layout col = lane&15
      bool ok = kvpos < Skv;
#pragma unroll
      for (int r = 0; r < 4; r++) s[t][r] = ok ? sacc[r] * scale : -1e30f;
    }

    // online softmax per row (row r lives in the 16 lanes of this quad)
#pragma unroll
    for (int r = 0; r < 4; r++) {
      float mx = fmaxf(fmaxf(s[0][r], s[1][r]), fmaxf(s[2][r], s[3][r]));
#pragma unroll
      for (int d = 1; d < 16; d <<= 1) mx = fmaxf(mx, __shfl_xor(mx, d));
      float mnew = fmaxf(m_r[r], mx);
      float alpha = __expf(m_r[r] - mnew);
      float sm = 0.f;
#pragma unroll
      for (int t = 0; t < 4; t++) { s[t][r] = __expf(s[t][r] - mnew); sm += s[t][r]; }
#pragma unroll
      for (int d = 1; d < 16; d <<= 1) sm += __shfl_xor(sm, d);
      l_r[r] = l_r[r] * alpha + sm;
      m_r[r] = mnew;
#pragma unroll
      for (int t = 0; t < 4; t++) o_acc[t][r] *= alpha;
    }

    // P: C-layout -> LDS -> A-layout
#pragma unroll
    for (int t = 0; t < 4; t++)
#pragma unroll
      for (int r = 0; r < 4; r++)
        lP[wave][quad * 4 + r][t * 16 + l15] = f2bf(s[t][r]);
    __syncthreads();
    v8s pf0 = *(const v8s*)&lP[wave][l15][quad * 8];
    v8s pf1 = *(const v8s*)&lP[wave][l15][32 + quad * 8];
#pragma unroll
    for (int t = 0; t < 4; t++) {
      v8s vf0 = *(const v8s*)&lV[t * 16 + l15][quad * 8];
      v8s vf1 = *(const v8s*)&lV[t * 16 + l15][32 + quad * 8];
      o_acc[t] = __builtin_amdgcn_mfma_f32_16x16x32_bf16(pf0, vf0, o_acc[t], 0, 0, 0);
      o_acc[t] = __builtin_amdgcn_mfma_f32_16x16x32_bf16(pf1, vf1, o_acc[t], 0, 0, 0);
    }
  }

  // epilogue: O /= l, write bf16 head-merged
  int orow0 = b * q_batch_rows + qt * 64 + wave * 16;
#pragma unroll
  for (int t = 0; t < 4; t++) {
#pragma unroll
    for (int r = 0; r < 4; r++) {
      float v = o_acc[t][r] / l_r[r];
      O[(size_t)(orow0 + quad * 4 + r) * o_rowstride + h * 64 + t * 16 + l15] = f2bf(v);
    }
  }
}

// ---------------------------------------------------------------------------
// Fused residual + LayerNorm over D=1024. 256 threads, 4 cols/thread.
// ---------------------------------------------------------------------------
__global__ __launch_bounds__(256)
void ln_kernel(const float* base, const float* __restrict__ delta,
               const float* __restrict__ g, const float* __restrict__ bb,
               float* outf, unsigned short* __restrict__ outb) {
  __shared__ float red[8];
  int row = blockIdx.x;
  int tid = threadIdx.x;
  float4 vb = ((const float4*)(base  + (size_t)row * 1024))[tid];
  float4 vd = ((const float4*)(delta + (size_t)row * 1024))[tid];
  float v0 = vb.x + vd.x, v1 = vb.y + vd.y, v2 = vb.z + vd.z, v3 = vb.w + vd.w;
  float s = v0 + v1 + v2 + v3;
  float q = v0 * v0 + v1 * v1 + v2 * v2 + v3 * v3;
#pragma unroll
  for (int d = 1; d < 64; d <<= 1) { s += __shfl_xor(s, d); q += __shfl_xor(q, d); }
  int wave = tid >> 6, lane = tid & 63;
  if (lane == 0) { red[wave] = s; red[4 + wave] = q; }
  __syncthreads();
  s = red[0] + red[1] + red[2] + red[3];
  q = red[4] + red[5] + red[6] + red[7];
  float mean = s * (1.f / 1024.f);
  float var  = q * (1.f / 1024.f) - mean * mean;
  float rstd = rsqrtf(var + 1e-5f);
  float4 gg  = ((const float4*)g)[tid];
  float4 bv  = ((const float4*)bb)[tid];
  float o0 = (v0 - mean) * rstd * gg.x + bv.x;
  float o1 = (v1 - mean) * rstd * gg.y + bv.y;
  float o2 = (v2 - mean) * rstd * gg.z + bv.z;
  float o3 = (v3 - mean) * rstd * gg.w + bv.w;
  if (outf) {
    float4 o; o.x = o0; o.y = o1; o.z = o2; o.w = o3;
    ((float4*)(outf + (size_t)row * 1024))[tid] = o;
  }
  if (outb) {
    ushort4 u; u.x = f2bf(o0); u.y = f2bf(o1); u.z = f2bf(o2); u.w = f2bf(o3);
    ((ushort4*)(outb + (size_t)row * 1024))[tid] = u;
  }
}

// ---------------------------------------------------------------------------
// Launch
// ---------------------------------------------------------------------------
extern "C" void kernel_launch(void* const* d_in, const int* in_sizes, int n_in,
                              void* d_out, int out_size, void* d_ws, size_t ws_size,
                              hipStream_t stream) {
  const float* x     = (const float*)d_in[0];
  const float* y     = (const float*)d_in[1];
  const float* w_qkv = (const float*)d_in[2];
  const float* b_qkv = (const float*)d_in[3];
  const float* w_so  = (const float*)d_in[4];
  const float* b_so  = (const float*)d_in[5];
  const float* w_q   = (const float*)d_in[6];
  const float* b_q   = (const float*)d_in[7];
  const float* w_k   = (const float*)d_in[8];
  const float* b_k   = (const float*)d_in[9];
  const float* w_v   = (const float*)d_in[10];
  const float* b_v   = (const float*)d_in[11];
  const float* w_co  = (const float*)d_in[12];
  const float* b_co  = (const float*)d_in[13];
  const float* w1    = (const float*)d_in[14];
  const float* b1    = (const float*)d_in[15];
  const float* w2    = (const float*)d_in[16];
  const float* b2    = (const float*)d_in[17];
  const float* w3    = (const float*)d_in[18];
  const float* b3    = (const float*)d_in[19];
  const float* ln_g  = (const float*)d_in[20];
  const float* ln_b  = (const float*)d_in[21];

  char* ws = (char*)d_ws;
  auto US = [&](size_t off) { return (unsigned short*)(ws + off); };
  auto FP = [&](size_t off) { return (float*)(ws + off); };

  // ws layout (bytes). Total ~168 MB.
  constexpr size_t o_wqkv = 0;                                 // [3072,1024] bf16
  constexpr size_t o_wso  = o_wqkv + 3072ull * 1024 * 2;       // [1024,1024]
  constexpr size_t o_wq   = o_wso  + 1024ull * 1024 * 2;
  constexpr size_t o_wk   = o_wq   + 1024ull * 1024 * 2;       // [1024,768]
  constexpr size_t o_wv   = o_wk   + 1024ull * 768 * 2;
  constexpr size_t o_wco  = o_wv   + 1024ull * 768 * 2;
  constexpr size_t o_w1   = o_wco  + 1024ull * 1024 * 2;       // [4096,1024]
  constexpr size_t o_w2   = o_w1   + 4096ull * 1024 * 2;       // [4096,4096]
  constexpr size_t o_w3   = o_w2   + 4096ull * 4096 * 2;       // [1024,4096]
  constexpr size_t o_xf   = o_w3   + 1024ull * 4096 * 2;       // x fp32 [4096,1024]
  constexpr size_t o_xbf  = o_xf   + 4096ull * 1024 * 4;       // x bf16
  constexpr size_t o_ybf  = o_xbf  + 4096ull * 1024 * 2;       // y bf16 [308,768]
  constexpr size_t o_dlt  = o_ybf  + 308ull * 768 * 2;         // delta fp32 [4096,1024]
  constexpr size_t o_R1   = o_dlt  + 4096ull * 1024 * 4;       // qkv bf16 [4096,3072]
  constexpr size_t o_attn = o_R1   + 4096ull * 3072 * 2;       // attn out bf16 [4096,1024]
  constexpr size_t o_R2   = o_attn + 4096ull * 1024 * 2;       // h2 bf16 [4096,4096]
  constexpr size_t o_qc = o_R1;
  constexpr size_t o_kc = o_R1 + 4096ull * 1024 * 2;
  constexpr size_t o_vc = o_kc + 308ull * 1024 * 2;
  constexpr size_t o_h1 = o_R1;
  constexpr size_t o_h2 = o_R2;

  dim3 tb(32, 8);
  // weight transpose-converts: in [K,N] fp32 -> out [N,K] bf16, grid (N/32,K/32)
  cvt_transpose<<<dim3(96, 32),  tb, 0, stream>>>(w_qkv, US(o_wqkv), 1024, 3072);
  cvt_transpose<<<dim3(32, 32),  tb, 0, stream>>>(w_so,  US(o_wso),  1024, 1024);
  cvt_transpose<<<dim3(32, 32),  tb, 0, stream>>>(w_q,   US(o_wq),   1024, 1024);
  cvt_transpose<<<dim3(32, 24),  tb, 0, stream>>>(w_k,   US(o_wk),   768,  1024);
  cvt_transpose<<<dim3(32, 24),  tb, 0, stream>>>(w_v,   US(o_wv),   768,  1024);
  cvt_transpose<<<dim3(32, 32),  tb, 0, stream>>>(w_co,  US(o_wco),  1024, 1024);
  cvt_transpose<<<dim3(128, 32), tb, 0, stream>>>(w1,    US(o_w1),   1024, 4096);
  cvt_transpose<<<dim3(128, 128),tb, 0, stream>>>(w2,    US(o_w2),   4096, 4096);
  cvt_transpose<<<dim3(32, 128), tb, 0, stream>>>(w3,    US(o_w3),   4096, 1024);

  cvt_f32_bf16<<<4096, 256, 0, stream>>>(x, US(o_xbf), 4096 * 1024 / 4);
  cvt_f32_bf16<<<231, 256, 0, stream>>>(y, US(o_ybf), 4 * 77 * 768 / 4);

  // --- self attention ---
  gemm_bf16<false, false, true><<<dim3(24, 32), 256, 0, stream>>>(
      US(o_xbf), US(o_wqkv), b_qkv, nullptr, US(o_R1), 4096, 3072, 1024);
  attn_kernel<<<dim3(16, 16, 4), 256, 0, stream>>>(
      US(o_R1), US(o_R1) + 1024, US(o_R1) + 2048, US(o_attn),
      3072, 3072, 1024, 1024, 1024, 1024, 0.125f);
  gemm_bf16<false, true, false><<<dim3(8, 32), 256, 0, stream>>>(
      US(o_attn), US(o_wso), b_so, FP(o_dlt), nullptr, 4096, 1024, 1024);
  ln_kernel<<<4096, 256, 0, stream>>>(x, FP(o_dlt), ln_g, ln_b, FP(o_xf), US(o_xbf));

  // --- cross attention ---
  gemm_bf16<false, false, true><<<dim3(8, 32), 256, 0, stream>>>(
      US(o_xbf), US(o_wq), b_q, nullptr, US(o_qc), 4096, 1024, 1024);
  gemm_bf16<false, false, true><<<dim3(8, 3), 256, 0, stream>>>(
      US(o_ybf), US(o_wk), b_k, nullptr, US(o_kc), 308, 1024, 768);
  gemm_bf16<false, false, true><<<dim3(8, 3), 256, 0, stream>>>(
      US(o_ybf), US(o_wv), b_v, nullptr, US(o_vc), 308, 1024, 768);
  attn_kernel<<<dim3(16, 16, 4), 256, 0, stream>>>(
      US(o_qc), US(o_kc), US(o_vc), US(o_attn),
      1024, 1024, 1024, 1024, 77, 77, 0.125f);
  gemm_bf16<false, true, false><<<dim3(8, 32), 256, 0, stream>>>(
      US(o_attn), US(o_wco), b_co, FP(o_dlt), nullptr, 4096, 1024, 1024);
  ln_kernel<<<4096, 256, 0, stream>>>(FP(o_xf), FP(o_dlt), ln_g, ln_b, FP(o_xf), US(o_xbf));

  // --- FFN ---
  gemm_bf16<true, false, true><<<dim3(32, 32), 256, 0, stream>>>(
      US(o_xbf), US(o_w1), b1, nullptr, US(o_h1), 4096, 4096, 1024);
  gemm_bf16<true, false, true><<<dim3(32, 32), 256, 0, stream>>>(
      US(o_h1), US(o_w2), b2, nullptr, US(o_h2), 4096, 4096, 4096);
  gemm_bf16<false, true, false><<<dim3(8, 32), 256, 0, stream>>>(
      US(o_h2), US(o_w3), b3, FP(o_dlt), nullptr, 4096, 1024, 4096);
  ln_kernel<<<4096, 256, 0, stream>>>(FP(o_xf), FP(o_dlt), ln_g, ln_b, (float*)d_out, nullptr);
}

// Round 5
// 875.253 us; speedup vs baseline: 1.0092x; 1.0092x over previous
//
#include <hip/hip_runtime.h>
#include <hip/hip_bf16.h>
#include <math.h>

// ---------------------------------------------------------------------------
// Types
// ---------------------------------------------------------------------------
typedef short v8s __attribute__((ext_vector_type(8)));   // 8 x bf16 bits (4 VGPR)
typedef float v4f __attribute__((ext_vector_type(4)));   // MFMA accumulator

__device__ __forceinline__ unsigned short f2bf(float f) {
  union { float f; unsigned u; } a; a.f = f;
  unsigned u = a.u + 0x7fffu + ((a.u >> 16) & 1u);   // RNE
  return (unsigned short)(u >> 16);
}

// async global->LDS, 16 B per lane; LDS dest = wave-uniform base + lane*16
__device__ __forceinline__ void gld_lds16(const unsigned short* g, unsigned short* l) {
  __builtin_amdgcn_global_load_lds(
      (const __attribute__((address_space(1))) void*)g,
      (__attribute__((address_space(3))) void*)l,
      16, 0, 0);
}

// ---------------------------------------------------------------------------
// fp32 -> bf16 (same layout), vectorized x4
// ---------------------------------------------------------------------------
__global__ void cvt_f32_bf16(const float* __restrict__ in,
                             unsigned short* __restrict__ out, int n4) {
  int i = blockIdx.x * blockDim.x + threadIdx.x;
  if (i >= n4) return;
  float4 v = reinterpret_cast<const float4*>(in)[i];
  ushort4 o;
  o.x = f2bf(v.x); o.y = f2bf(v.y); o.z = f2bf(v.z); o.w = f2bf(v.w);
  reinterpret_cast<ushort4*>(out)[i] = o;
}

// ---------------------------------------------------------------------------
// fp32 [K,N] -> bf16 [N,K] transpose-convert (weights). block (32,8)
// ---------------------------------------------------------------------------
__global__ void cvt_transpose(const float* __restrict__ in,
                              unsigned short* __restrict__ out, int K, int N) {
  __shared__ float t[32][33];
  int bx = blockIdx.x, by = blockIdx.y;
  int tx = threadIdx.x, ty = threadIdx.y;
#pragma unroll
  for (int i = 0; i < 4; i++) {
    int k = by * 32 + ty + i * 8;
    t[ty + i * 8][tx] = in[(size_t)k * N + bx * 32 + tx];
  }
  __syncthreads();
#pragma unroll
  for (int i = 0; i < 4; i++) {
    int n = bx * 32 + ty + i * 8;
    out[(size_t)n * K + by * 32 + tx] = f2bf(t[tx][ty + i * 8]);
  }
}

// ---------------------------------------------------------------------------
// bf16 MFMA GEMM: C[M,N] = act(A[M,K] @ B[K,N] + bias)
// A row-major bf16, BT = B^T row-major [N,K] bf16.
// 256 threads = 4 waves, tile 128x128, BK=32 DOUBLE-BUFFERED (2x8KB x2 arrays
// = 32 KB LDS), each wave 64x64 (4x4 MFMA tiles).
// K-loop: barrier -> issue async loads for tile k+1 into other buffer ->
// compute tile k. The vmcnt(0) drain before s_barrier then waits on loads
// issued one full compute phase earlier (prefetch distance 1).
// LDS geometry: PAIRED ROWS -> 64 lines x 128 B (full 32-bank lines; round-3's
// zero-conflict geometry). Row r: line r>>1, half r&1. Global k-chunk `quad`
// of row r sits at chunk pos (r&1)*4 + (quad ^ ((r>>1)&3)) -> every 16-lane
// frag-read group covers all 8 chunk positions exactly 2x = free 2-way.
// Swizzle realized by permuting per-lane GLOBAL source chunk (DMA map fixed):
// thread t writes line L=t>>3, pos p=t&7  => row 2L+(p>>2), chunk (p&3)^(L&3).
// Ragged M: OOB rows read workspace garbage (mapped), discarded at store.
// N must be mult of 128, K mult of 32.
// ---------------------------------------------------------------------------
template<bool RELU, bool OUTF, bool OUTB>
__global__ __launch_bounds__(256)
void gemm_bf16(const unsigned short* __restrict__ A,
               const unsigned short* __restrict__ BT,
               const float* __restrict__ bias,
               float* __restrict__ Cf, unsigned short* __restrict__ Cb,
               int M, int N, int K) {
  __shared__ __align__(16) unsigned short lA[2][64 * 64];   // 2 x 8 KB
  __shared__ __align__(16) unsigned short lB[2][64 * 64];
  int tid  = threadIdx.x;
  int lane = tid & 63;
  int wave = tid >> 6;
  int wr = (wave >> 1) * 64;
  int wc = (wave & 1) * 64;
  int quad = lane >> 4;
  int l15  = lane & 15;
  int m0 = blockIdx.y * 128;
  int n0 = blockIdx.x * 128;

  // staging source map (issue 0 = rows 0..63, issue 1 = +64):
  int L0 = tid >> 3;
  int r0 = 2 * L0 + ((tid >> 2) & 1);
  int c0 = (tid & 3) ^ (L0 & 3);
  const unsigned short* gA = A  + (size_t)(m0 + r0) * K + c0 * 8;
  const unsigned short* gB = BT + (size_t)(n0 + r0) * K + c0 * 8;
  const size_t half = (size_t)64 * K;       // +64 rows (issue 1)

  // frag read offset: row r = {wr|wc} + i*16 + l15, global chunk = quad:
  //   addr = (r>>1)*64 + ((r&1)*4 + (quad ^ ((r>>1)&3)))*8
  // (r>>1)&3 reduces to (l15>>1)&3 (wr/2, i*8 are mult of 4)
  int sw = quad ^ ((l15 >> 1) & 3);
  int rdoff = (l15 >> 1) * 64 + ((l15 & 1) * 4 + sw) * 8;   // shorts

  const v4f vzero = {0.f, 0.f, 0.f, 0.f};
  v4f acc[4][4];
#pragma unroll
  for (int i = 0; i < 4; i++)
#pragma unroll
    for (int j = 0; j < 4; j++) acc[i][j] = vzero;

  // prologue: issue tile 0 into buffer 0
  {
    unsigned short* dA = &lA[0][0] + wave * 512;
    unsigned short* dB = &lB[0][0] + wave * 512;
    gld_lds16(gA, dA);
    gld_lds16(gA + half, dA + 2048);
    gld_lds16(gB, dB);
    gld_lds16(gB + half, dB + 2048);
  }

  int nk = K >> 5;
  for (int kk = 0; kk < nk; kk++) {
    __syncthreads();          // tile kk ready (loads issued 1 phase ago); prev reads done
    if (kk + 1 < nk) {
      int k1 = (kk + 1) << 5;
      int b1 = (kk + 1) & 1;
      unsigned short* dA = &lA[b1][0] + wave * 512;
      unsigned short* dB = &lB[b1][0] + wave * 512;
      gld_lds16(gA + k1, dA);
      gld_lds16(gA + k1 + half, dA + 2048);
      gld_lds16(gB + k1, dB);
      gld_lds16(gB + k1 + half, dB + 2048);
    }
    int b = kk & 1;
    v8s aF[4], bF[4];
#pragma unroll
    for (int i = 0; i < 4; i++) aF[i] = *(const v8s*)&lA[b][wr * 32 + i * 512 + rdoff];
#pragma unroll
    for (int j = 0; j < 4; j++) bF[j] = *(const v8s*)&lB[b][wc * 32 + j * 512 + rdoff];
#pragma unroll
    for (int i = 0; i < 4; i++)
#pragma unroll
      for (int j = 0; j < 4; j++)
        acc[i][j] = __builtin_amdgcn_mfma_f32_16x16x32_bf16(aF[i], bF[j], acc[i][j], 0, 0, 0);
  }

  // epilogue: C/D layout col=lane&15, row=quad*4+reg
#pragma unroll
  for (int j = 0; j < 4; j++) {
    int col = n0 + wc + j * 16 + l15;
    float bv = bias ? bias[col] : 0.f;
#pragma unroll
    for (int i = 0; i < 4; i++) {
#pragma unroll
      for (int r = 0; r < 4; r++) {
        int row = m0 + wr + i * 16 + quad * 4 + r;
        if (row < M) {
          float v = acc[i][j][r] + bv;
          if (RELU) v = fmaxf(v, 0.f);
          if (OUTF) Cf[(size_t)row * N + col] = v;
          if (OUTB) Cb[(size_t)row * N + col] = f2bf(v);
        }
      }
    }
  }
}

// ---------------------------------------------------------------------------
// Flash-style MFMA attention. grid (Sq/64, H, B), 256 threads = 4 waves.
// One WG: 64 query rows of one (b,h); KV chunks of 64, online softmax.
// Q/K/V bf16 with row stride; O bf16 [B*Sq, H*64] head-merged.
// ---------------------------------------------------------------------------
__global__ __launch_bounds__(256)
void attn_kernel(const unsigned short* __restrict__ Q,
                 const unsigned short* __restrict__ K,
                 const unsigned short* __restrict__ V,
                 unsigned short* __restrict__ O,
                 int q_rowstride, int kv_rowstride, int o_rowstride,
                 int q_batch_rows, int kv_batch_rows, int Skv, float scale) {
  __shared__ __align__(16) unsigned short lK[64][72];      // [kv][d]
  __shared__ __align__(16) unsigned short lV[64][72];      // transposed: [d][kv]
  __shared__ __align__(16) unsigned short lP[4][16][72];   // per-wave P (A-layout src)
  int tid  = threadIdx.x;
  int lane = tid & 63;
  int wave = tid >> 6;
  int quad = lane >> 4;
  int l15  = lane & 15;
  int qt = blockIdx.x, h = blockIdx.y, b = blockIdx.z;

  const unsigned short* Qb = Q + (size_t)b * q_batch_rows * q_rowstride + h * 64;
  const unsigned short* Kb = K + (size_t)b * kv_batch_rows * kv_rowstride + h * 64;
  const unsigned short* Vb = V + (size_t)b * kv_batch_rows * kv_rowstride + h * 64;

  // Q A-frags (rows qt*64 + wave*16 + l15, k = c*32 + quad*8 + j)
  v8s qf0, qf1;
  {
    const unsigned short* qr = Qb + (size_t)(qt * 64 + wave * 16 + l15) * q_rowstride + quad * 8;
    qf0 = *(const v8s*)(qr);
    qf1 = *(const v8s*)(qr + 32);
  }

  const v4f vzero = {0.f, 0.f, 0.f, 0.f};
  v4f o_acc[4];
#pragma unroll
  for (int t = 0; t < 4; t++) o_acc[t] = vzero;
  float m_r[4], l_r[4];
#pragma unroll
  for (int r = 0; r < 4; r++) { m_r[r] = -1e30f; l_r[r] = 0.f; }

  int sr = tid >> 2;            // kv row in chunk 0..63
  int sc = (tid & 3) * 16;      // 0/16/32/48

  int nch = (Skv + 63) >> 6;
  for (int ch = 0; ch < nch; ch++) {
    int base = ch * 64;
    int gr = base + sr;
    v8s k0v = {}, k1v = {}, v0v = {}, v1v = {};
    if (gr < Skv) {
      const unsigned short* kp = Kb + (size_t)gr * kv_rowstride + sc;
      const unsigned short* vp = Vb + (size_t)gr * kv_rowstride + sc;
      k0v = *(const v8s*)kp;  k1v = *(const v8s*)(kp + 8);
      v0v = *(const v8s*)vp;  v1v = *(const v8s*)(vp + 8);
    }
    __syncthreads();            // prev chunk's lV/lP reads done
    *(v8s*)&lK[sr][sc]     = k0v;
    *(v8s*)&lK[sr][sc + 8] = k1v;
#pragma unroll
    for (int e = 0; e < 8; e++) {
      lV[sc + e][sr]     = (unsigned short)v0v[e];
      lV[sc + 8 + e][sr] = (unsigned short)v1v[e];
    }
    __syncthreads();

    // S = Q K^T for 4 kv sub-tiles of 16
    float s[4][4];
#pragma unroll
    for (int t = 0; t < 4; t++) {
      v8s kf0 = *(const v8s*)&lK[t * 16 + l15][quad * 8];
      v8s kf1 = *(const v8s*)&lK[t * 16 + l15][32 + quad * 8];
      v4f sacc = vzero;
      sacc = __builtin_amdgcn_mfma_f32_16x16x32_bf16(qf0, kf0, sacc, 0, 0, 0);
      sacc = __builtin_amdgcn_mfma_f32_16x16x32_bf16(qf1, kf1, sacc, 0, 0, 0);
      int kvpos = base + t * 16 + l15;     // C-layout col = lane&15
      bool ok = kvpos < Skv;
#pragma unroll
      for (int r = 0; r < 4; r++) s[t][r] = ok ? sacc[r] * scale : -1e30f;
    }

    // online softmax per row (row r lives in the 16 lanes of this quad)
#pragma unroll
    for (int r = 0; r < 4; r++) {
      float mx = fmaxf(fmaxf(s[0][r], s[1][r]), fmaxf(s[2][r], s[3][r]));
#pragma unroll
      for (int d = 1; d < 16; d <<= 1) mx = fmaxf(mx, __shfl_xor(mx, d));
      float mnew = fmaxf(m_r[r], mx);
      float alpha = __expf(m_r[r] - mnew);
      float sm = 0.f;
#pragma unroll
      for (int t = 0; t < 4; t++) { s[t][r] = __expf(s[t][r] - mnew); sm += s[t][r]; }
#pragma unroll
      for (int d = 1; d < 16; d <<= 1) sm += __shfl_xor(sm, d);
      l_r[r] = l_r[r] * alpha + sm;
      m_r[r] = mnew;
#pragma unroll
      for (int t = 0; t < 4; t++) o_acc[t][r] *= alpha;
    }

    // P: C-layout -> LDS -> A-layout
#pragma unroll
    for (int t = 0; t < 4; t++)
#pragma unroll
      for (int r = 0; r < 4; r++)
        lP[wave][quad * 4 + r][t * 16 + l15] = f2bf(s[t][r]);
    __syncthreads();
    v8s pf0 = *(const v8s*)&lP[wave][l15][quad * 8];
    v8s pf1 = *(const v8s*)&lP[wave][l15][32 + quad * 8];
#pragma unroll
    for (int t = 0; t < 4; t++) {
      v8s vf0 = *(const v8s*)&lV[t * 16 + l15][quad * 8];
      v8s vf1 = *(const v8s*)&lV[t * 16 + l15][32 + quad * 8];
      o_acc[t] = __builtin_amdgcn_mfma_f32_16x16x32_bf16(pf0, vf0, o_acc[t], 0, 0, 0);
      o_acc[t] = __builtin_amdgcn_mfma_f32_16x16x32_bf16(pf1, vf1, o_acc[t], 0, 0, 0);
    }
  }

  // epilogue: O /= l, write bf16 head-merged
  int orow0 = b * q_batch_rows + qt * 64 + wave * 16;
#pragma unroll
  for (int t = 0; t < 4; t++) {
#pragma unroll
    for (int r = 0; r < 4; r++) {
      float v = o_acc[t][r] / l_r[r];
      O[(size_t)(orow0 + quad * 4 + r) * o_rowstride + h * 64 + t * 16 + l15] = f2bf(v);
    }
  }
}

// ---------------------------------------------------------------------------
// Fused residual + LayerNorm over D=1024. 256 threads, 4 cols/thread.
// ---------------------------------------------------------------------------
__global__ __launch_bounds__(256)
void ln_kernel(const float* base, const float* __restrict__ delta,
               const float* __restrict__ g, const float* __restrict__ bb,
               float* outf, unsigned short* __restrict__ outb) {
  __shared__ float red[8];
  int row = blockIdx.x;
  int tid = threadIdx.x;
  float4 vb = ((const float4*)(base  + (size_t)row * 1024))[tid];
  float4 vd = ((const float4*)(delta + (size_t)row * 1024))[tid];
  float v0 = vb.x + vd.x, v1 = vb.y + vd.y, v2 = vb.z + vd.z, v3 = vb.w + vd.w;
  float s = v0 + v1 + v2 + v3;
  float q = v0 * v0 + v1 * v1 + v2 * v2 + v3 * v3;
#pragma unroll
  for (int d = 1; d < 64; d <<= 1) { s += __shfl_xor(s, d); q += __shfl_xor(q, d); }
  int wave = tid >> 6, lane = tid & 63;
  if (lane == 0) { red[wave] = s; red[4 + wave] = q; }
  __syncthreads();
  s = red[0] + red[1] + red[2] + red[3];
  q = red[4] + red[5] + red[6] + red[7];
  float mean = s * (1.f / 1024.f);
  float var  = q * (1.f / 1024.f) - mean * mean;
  float rstd = rsqrtf(var + 1e-5f);
  float4 gg  = ((const float4*)g)[tid];
  float4 bv  = ((const float4*)bb)[tid];
  float o0 = (v0 - mean) * rstd * gg.x + bv.x;
  float o1 = (v1 - mean) * rstd * gg.y + bv.y;
  float o2 = (v2 - mean) * rstd * gg.z + bv.z;
  float o3 = (v3 - mean) * rstd * gg.w + bv.w;
  if (outf) {
    float4 o; o.x = o0; o.y = o1; o.z = o2; o.w = o3;
    ((float4*)(outf + (size_t)row * 1024))[tid] = o;
  }
  if (outb) {
    ushort4 u; u.x = f2bf(o0); u.y = f2bf(o1); u.z = f2bf(o2); u.w = f2bf(o3);
    ((ushort4*)(outb + (size_t)row * 1024))[tid] = u;
  }
}

// ---------------------------------------------------------------------------
// Launch
// ---------------------------------------------------------------------------
extern "C" void kernel_launch(void* const* d_in, const int* in_sizes, int n_in,
                              void* d_out, int out_size, void* d_ws, size_t ws_size,
                              hipStream_t stream) {
  const float* x     = (const float*)d_in[0];
  const float* y     = (const float*)d_in[1];
  const float* w_qkv = (const float*)d_in[2];
  const float* b_qkv = (const float*)d_in[3];
  const float* w_so  = (const float*)d_in[4];
  const float* b_so  = (const float*)d_in[5];
  const float* w_q   = (const float*)d_in[6];
  const float* b_q   = (const float*)d_in[7];
  const float* w_k   = (const float*)d_in[8];
  const float* b_k   = (const float*)d_in[9];
  const float* w_v   = (const float*)d_in[10];
  const float* b_v   = (const float*)d_in[11];
  const float* w_co  = (const float*)d_in[12];
  const float* b_co  = (const float*)d_in[13];
  const float* w1    = (const float*)d_in[14];
  const float* b1    = (const float*)d_in[15];
  const float* w2    = (const float*)d_in[16];
  const float* b2    = (const float*)d_in[17];
  const float* w3    = (const float*)d_in[18];
  const float* b3    = (const float*)d_in[19];
  const float* ln_g  = (const float*)d_in[20];
  const float* ln_b  = (const float*)d_in[21];

  char* ws = (char*)d_ws;
  auto US = [&](size_t off) { return (unsigned short*)(ws + off); };
  auto FP = [&](size_t off) { return (float*)(ws + off); };

  // ws layout (bytes). Total ~168 MB.
  constexpr size_t o_wqkv = 0;                                 // [3072,1024] bf16
  constexpr size_t o_wso  = o_wqkv + 3072ull * 1024 * 2;       // [1024,1024]
  constexpr size_t o_wq   = o_wso  + 1024ull * 1024 * 2;
  constexpr size_t o_wk   = o_wq   + 1024ull * 1024 * 2;       // [1024,768]
  constexpr size_t o_wv   = o_wk   + 1024ull * 768 * 2;
  constexpr size_t o_wco  = o_wv   + 1024ull * 768 * 2;
  constexpr size_t o_w1   = o_wco  + 1024ull * 1024 * 2;       // [4096,1024]
  constexpr size_t o_w2   = o_w1   + 4096ull * 1024 * 2;       // [4096,4096]
  constexpr size_t o_w3   = o_w2   + 4096ull * 4096 * 2;       // [1024,4096]
  constexpr size_t o_xf   = o_w3   + 1024ull * 4096 * 2;       // x fp32 [4096,1024]
  constexpr size_t o_xbf  = o_xf   + 4096ull * 1024 * 4;       // x bf16
  constexpr size_t o_ybf  = o_xbf  + 4096ull * 1024 * 2;       // y bf16 [308,768]
  constexpr size_t o_dlt  = o_ybf  + 308ull * 768 * 2;         // delta fp32 [4096,1024]
  constexpr size_t o_R1   = o_dlt  + 4096ull * 1024 * 4;       // qkv bf16 [4096,3072]
  constexpr size_t o_attn = o_R1   + 4096ull * 3072 * 2;       // attn out bf16 [4096,1024]
  constexpr size_t o_R2   = o_attn + 4096ull * 1024 * 2;       // h2 bf16 [4096,4096]
  constexpr size_t o_qc = o_R1;
  constexpr size_t o_kc = o_R1 + 4096ull * 1024 * 2;
  constexpr size_t o_vc = o_kc + 308ull * 1024 * 2;
  constexpr size_t o_h1 = o_R1;
  constexpr size_t o_h2 = o_R2;

  dim3 tb(32, 8);
  // weight transpose-converts: in [K,N] fp32 -> out [N,K] bf16, grid (N/32,K/32)
  cvt_transpose<<<dim3(96, 32),  tb, 0, stream>>>(w_qkv, US(o_wqkv), 1024, 3072);
  cvt_transpose<<<dim3(32, 32),  tb, 0, stream>>>(w_so,  US(o_wso),  1024, 1024);
  cvt_transpose<<<dim3(32, 32),  tb, 0, stream>>>(w_q,   US(o_wq),   1024, 1024);
  cvt_transpose<<<dim3(32, 24),  tb, 0, stream>>>(w_k,   US(o_wk),   768,  1024);
  cvt_transpose<<<dim3(32, 24),  tb, 0, stream>>>(w_v,   US(o_wv),   768,  1024);
  cvt_transpose<<<dim3(32, 32),  tb, 0, stream>>>(w_co,  US(o_wco),  1024, 1024);
  cvt_transpose<<<dim3(128, 32), tb, 0, stream>>>(w1,    US(o_w1),   1024, 4096);
  cvt_transpose<<<dim3(128, 128),tb, 0, stream>>>(w2,    US(o_w2),   4096, 4096);
  cvt_transpose<<<dim3(32, 128), tb, 0, stream>>>(w3,    US(o_w3),   4096, 1024);

  cvt_f32_bf16<<<4096, 256, 0, stream>>>(x, US(o_xbf), 4096 * 1024 / 4);
  cvt_f32_bf16<<<231, 256, 0, stream>>>(y, US(o_ybf), 4 * 77 * 768 / 4);

  // --- self attention ---
  gemm_bf16<false, false, true><<<dim3(24, 32), 256, 0, stream>>>(
      US(o_xbf), US(o_wqkv), b_qkv, nullptr, US(o_R1), 4096, 3072, 1024);
  attn_kernel<<<dim3(16, 16, 4), 256, 0, stream>>>(
      US(o_R1), US(o_R1) + 1024, US(o_R1) + 2048, US(o_attn),
      3072, 3072, 1024, 1024, 1024, 1024, 0.125f);
  gemm_bf16<false, true, false><<<dim3(8, 32), 256, 0, stream>>>(
      US(o_attn), US(o_wso), b_so, FP(o_dlt), nullptr, 4096, 1024, 1024);
  ln_kernel<<<4096, 256, 0, stream>>>(x, FP(o_dlt), ln_g, ln_b, FP(o_xf), US(o_xbf));

  // --- cross attention ---
  gemm_bf16<false, false, true><<<dim3(8, 32), 256, 0, stream>>>(
      US(o_xbf), US(o_wq), b_q, nullptr, US(o_qc), 4096, 1024, 1024);
  gemm_bf16<false, false, true><<<dim3(8, 3), 256, 0, stream>>>(
      US(o_ybf), US(o_wk), b_k, nullptr, US(o_kc), 308, 1024, 768);
  gemm_bf16<false, false, true><<<dim3(8, 3), 256, 0, stream>>>(
      US(o_ybf), US(o_wv), b_v, nullptr, US(o_vc), 308, 1024, 768);
  attn_kernel<<<dim3(16, 16, 4), 256, 0, stream>>>(
      US(o_qc), US(o_kc), US(o_vc), US(o_attn),
      1024, 1024, 1024, 1024, 77, 77, 0.125f);
  gemm_bf16<false, true, false><<<dim3(8, 32), 256, 0, stream>>>(
      US(o_attn), US(o_wco), b_co, FP(o_dlt), nullptr, 4096, 1024, 1024);
  ln_kernel<<<4096, 256, 0, stream>>>(FP(o_xf), FP(o_dlt), ln_g, ln_b, FP(o_xf), US(o_xbf));

  // --- FFN ---
  gemm_bf16<true, false, true><<<dim3(32, 32), 256, 0, stream>>>(
      US(o_xbf), US(o_w1), b1, nullptr, US(o_h1), 4096, 4096, 1024);
  gemm_bf16<true, false, true><<<dim3(32, 32), 256, 0, stream>>>(
      US(o_h1), US(o_w2), b2, nullptr, US(o_h2), 4096, 4096, 4096);
  gemm_bf16<false, true, false><<<dim3(8, 32), 256, 0, stream>>>(
      US(o_h2), US(o_w3), b3, FP(o_dlt), nullptr, 4096, 1024, 4096);
  ln_kernel<<<4096, 256, 0, stream>>>(FP(o_xf), FP(o_dlt), ln_g, ln_b, (float*)d_out, nullptr);
}

// Round 6
// 811.513 us; speedup vs baseline: 1.0885x; 1.0785x over previous
//
#include <hip/hip_runtime.h>
#include <hip/hip_bf16.h>
#include <math.h>

// ---------------------------------------------------------------------------
// Types
// ---------------------------------------------------------------------------
typedef short v8s __attribute__((ext_vector_type(8)));   // 8 x bf16 bits (4 VGPR)
typedef short v4s __attribute__((ext_vector_type(4)));   // 8 B
typedef float v4f __attribute__((ext_vector_type(4)));   // MFMA accumulator

__device__ __forceinline__ unsigned short f2bf(float f) {
  union { float f; unsigned u; } a; a.f = f;
  unsigned u = a.u + 0x7fffu + ((a.u >> 16) & 1u);   // RNE
  return (unsigned short)(u >> 16);
}

// async global->LDS, 16 B per lane; LDS dest = wave-uniform base + lane*16
__device__ __forceinline__ void gld_lds16(const unsigned short* g, unsigned short* l) {
  __builtin_amdgcn_global_load_lds(
      (const __attribute__((address_space(1))) void*)g,
      (__attribute__((address_space(3))) void*)l,
      16, 0, 0);
}

// ---------------------------------------------------------------------------
// fp32 -> bf16 (same layout), vectorized x4
// ---------------------------------------------------------------------------
__global__ void cvt_f32_bf16(const float* __restrict__ in,
                             unsigned short* __restrict__ out, int n4) {
  int i = blockIdx.x * blockDim.x + threadIdx.x;
  if (i >= n4) return;
  float4 v = reinterpret_cast<const float4*>(in)[i];
  ushort4 o;
  o.x = f2bf(v.x); o.y = f2bf(v.y); o.z = f2bf(v.z); o.w = f2bf(v.w);
  reinterpret_cast<ushort4*>(out)[i] = o;
}

// ---------------------------------------------------------------------------
// fp32 [K,N] -> bf16 [N,K] transpose-convert (weights). block (32,8)
// ---------------------------------------------------------------------------
__global__ void cvt_transpose(const float* __restrict__ in,
                              unsigned short* __restrict__ out, int K, int N) {
  __shared__ float t[32][33];
  int bx = blockIdx.x, by = blockIdx.y;
  int tx = threadIdx.x, ty = threadIdx.y;
#pragma unroll
  for (int i = 0; i < 4; i++) {
    int k = by * 32 + ty + i * 8;
    t[ty + i * 8][tx] = in[(size_t)k * N + bx * 32 + tx];
  }
  __syncthreads();
#pragma unroll
  for (int i = 0; i < 4; i++) {
    int n = bx * 32 + ty + i * 8;
    out[(size_t)n * K + by * 32 + tx] = f2bf(t[tx][ty + i * 8]);
  }
}

// ---------------------------------------------------------------------------
// bf16 [rows, rowstride] per-head block -> Vt[b][h][64][kvpad] (V transpose)
// grid (ceil(Skv/64), H, B), 256 threads. OOB kv rows -> zero.
// ---------------------------------------------------------------------------
__global__ __launch_bounds__(256)
void transpose_v(const unsigned short* __restrict__ V,
                 unsigned short* __restrict__ Vt,
                 int rowstride, int batch_rows, int Skv, int kvpad) {
  __shared__ __align__(16) unsigned short t[64][80];
  int ch = blockIdx.x, h = blockIdx.y, b = blockIdx.z;
  int tid = threadIdx.x;
  int sr = tid >> 2, sc = (tid & 3) * 16;
  int gr = ch * 64 + sr;
  v8s v0 = {}, v1 = {};
  if (gr < Skv) {
    const unsigned short* p = V + (size_t)(b * batch_rows + gr) * rowstride + h * 64 + sc;
    v0 = *(const v8s*)p; v1 = *(const v8s*)(p + 8);
  }
  *(v8s*)&t[sr][sc]     = v0;
  *(v8s*)&t[sr][sc + 8] = v1;
  __syncthreads();
  int d  = tid >> 2;
  int k0 = (tid & 3) * 16;
  unsigned short* o = Vt + ((size_t)(b * 16 + h) * 64 + d) * kvpad + ch * 64 + k0;
  v8s o0, o1;
#pragma unroll
  for (int e = 0; e < 8; e++) { o0[e] = t[k0 + e][d]; o1[e] = t[k0 + 8 + e][d]; }
  *(v8s*)o       = o0;
  *(v8s*)(o + 8) = o1;
}

// ---------------------------------------------------------------------------
// bf16 MFMA GEMM (R3 structure, proven 719 TF / 0 conflicts):
//   C[M,N] = act(A[M,K] @ B[K,N] + bias),  A row-major, BT=B^T [N,K].
// 256 threads = 4 waves, tile 128x128, BK=64, wave 64x64 (4x4 MFMA tiles).
// global_load_lds w=16 into lA/lB [128][64] (32 KB). XOR swizzle: LDS chunk
// slot c of row r holds global chunk c^(r&7) -> frag reads conflict-free.
// Split-K via blockIdx.z: part z covers K range [z*Kred, (z+1)*Kred); z=0
// writes Cf/Cb (+bias), z=1 writes Cf2 (no bias). ld = row stride of A/BT.
// Ragged M: OOB rows read mapped garbage, discarded at store.
// N mult of 128, Kred mult of 64.
// ---------------------------------------------------------------------------
template<bool RELU, bool OUTF, bool OUTB>
__global__ __launch_bounds__(256)
void gemm_bf16(const unsigned short* __restrict__ A,
               const unsigned short* __restrict__ BT,
               const float* __restrict__ bias,
               float* __restrict__ Cf, float* __restrict__ Cf2,
               unsigned short* __restrict__ Cb,
               int M, int N, int Kred, int ld) {
  __shared__ __align__(16) unsigned short lA[128 * 64];   // 16 KB
  __shared__ __align__(16) unsigned short lB[128 * 64];
  int tid  = threadIdx.x;
  int lane = tid & 63;
  int wave = tid >> 6;
  int wr = (wave >> 1) * 64;
  int wc = (wave & 1) * 64;
  int quad = lane >> 4;
  int l15  = lane & 15;
  int m0 = blockIdx.y * 128;
  int n0 = blockIdx.x * 128;
  int z  = blockIdx.z;

  const unsigned short* Az = A  + (size_t)z * Kred;
  const unsigned short* Bz = BT + (size_t)z * Kred;
  float* Cfo = z ? Cf2 : Cf;
  const float* biasz = z ? nullptr : bias;

  // staging map: row = i*32 + (tid>>3), source chunk = (tid&7) ^ (row&7)
  int srow   = tid >> 3;                       // 0..31
  int schunk = (tid & 7) ^ (srow & 7);
  const unsigned short* gA = Az + (size_t)(m0 + srow) * ld + schunk * 8;
  const unsigned short* gB = Bz + (size_t)(n0 + srow) * ld + schunk * 8;
  unsigned short* ldsA = lA + wave * 512;      // wave-uniform byte base = wave*1024
  unsigned short* ldsB = lB + wave * 512;
  const size_t rowblk = (size_t)32 * ld;

  const v4f vzero = {0.f, 0.f, 0.f, 0.f};
  v4f acc[4][4];
#pragma unroll
  for (int i = 0; i < 4; i++)
#pragma unroll
    for (int j = 0; j < 4; j++) acc[i][j] = vzero;

  for (int k0 = 0; k0 < Kred; k0 += 64) {
#pragma unroll
    for (int i = 0; i < 4; i++) {
      gld_lds16(gA + k0 + i * rowblk, ldsA + i * 2048);
      gld_lds16(gB + k0 + i * rowblk, ldsB + i * 2048);
    }
    __syncthreads();                       // drains vmcnt -> LDS tile ready
#pragma unroll
    for (int s = 0; s < 2; s++) {
      v8s aF[4], bF[4];
#pragma unroll
      for (int i = 0; i < 4; i++)
        aF[i] = *(const v8s*)&lA[(wr + i * 16 + l15) * 64 + (((s * 4 + quad) ^ (l15 & 7)) * 8)];
#pragma unroll
      for (int j = 0; j < 4; j++)
        bF[j] = *(const v8s*)&lB[(wc + j * 16 + l15) * 64 + (((s * 4 + quad) ^ (l15 & 7)) * 8)];
#pragma unroll
      for (int i = 0; i < 4; i++)
#pragma unroll
        for (int j = 0; j < 4; j++)
          acc[i][j] = __builtin_amdgcn_mfma_f32_16x16x32_bf16(aF[i], bF[j], acc[i][j], 0, 0, 0);
    }
    __syncthreads();                       // frag reads done before next overwrite
  }

  // epilogue: C/D layout col=lane&15, row=quad*4+reg
#pragma unroll
  for (int j = 0; j < 4; j++) {
    int col = n0 + wc + j * 16 + l15;
    float bv = biasz ? biasz[col] : 0.f;
#pragma unroll
    for (int i = 0; i < 4; i++) {
#pragma unroll
      for (int r = 0; r < 4; r++) {
        int row = m0 + wr + i * 16 + quad * 4 + r;
        if (row < M) {
          float v = acc[i][j][r] + bv;
          if (RELU) v = fmaxf(v, 0.f);
          if (OUTF) Cfo[(size_t)row * N + col] = v;
          if (OUTB && !z) Cb[(size_t)row * N + col] = f2bf(v);
        }
      }
    }
  }
}

// ---------------------------------------------------------------------------
// Flash-style MFMA attention. grid (Sq/64, H, B), 256 threads = 4 waves.
// One WG: 64 query rows of one (b,h); KV chunks of 64, online softmax.
// K bf16 rows; V pre-transposed Vt[b][h][64][kvpad] (vector LDS staging).
// O bf16 [B*Sq, H*64] head-merged. lP is per-wave -> no barrier in PV phase.
// ---------------------------------------------------------------------------
__global__ __launch_bounds__(256)
void attn_kernel(const unsigned short* __restrict__ Q,
                 const unsigned short* __restrict__ K,
                 const unsigned short* __restrict__ Vt,
                 unsigned short* __restrict__ O,
                 int q_rowstride, int kv_rowstride, int o_rowstride,
                 int q_batch_rows, int kv_batch_rows, int Skv, int kvpad,
                 float scale) {
  __shared__ __align__(16) unsigned short lK[64][72];      // [kv][d]
  __shared__ __align__(16) unsigned short lV[64][72];      // [d][kv]
  __shared__ __align__(16) unsigned short lP[4][16][72];   // per-wave P (A-layout src)
  int tid  = threadIdx.x;
  int lane = tid & 63;
  int wave = tid >> 6;
  int quad = lane >> 4;
  int l15  = lane & 15;
  int qt = blockIdx.x, h = blockIdx.y, b = blockIdx.z;

  const unsigned short* Qb  = Q  + (size_t)b * q_batch_rows * q_rowstride + h * 64;
  const unsigned short* Kb  = K  + (size_t)b * kv_batch_rows * kv_rowstride + h * 64;
  const unsigned short* Vtb = Vt + ((size_t)(b * 16 + h) * 64) * kvpad;

  // Q A-frags (rows qt*64 + wave*16 + l15, k = c*32 + quad*8 + j)
  v8s qf0, qf1;
  {
    const unsigned short* qr = Qb + (size_t)(qt * 64 + wave * 16 + l15) * q_rowstride + quad * 8;
    qf0 = *(const v8s*)(qr);
    qf1 = *(const v8s*)(qr + 32);
  }

  const v4f vzero = {0.f, 0.f, 0.f, 0.f};
  v4f o_acc[4];
#pragma unroll
  for (int t = 0; t < 4; t++) o_acc[t] = vzero;
  float m_r[4], l_r[4];
#pragma unroll
  for (int r = 0; r < 4; r++) { m_r[r] = -1e30f; l_r[r] = 0.f; }

  int sr = tid >> 2;            // kv row (K) / d row (V) in chunk, 0..63
  int sc = (tid & 3) * 16;      // 0/16/32/48

  int nch = (Skv + 63) >> 6;
  for (int ch = 0; ch < nch; ch++) {
    int base = ch * 64;
    int gr = base + sr;
    v8s k0v = {}, k1v = {};
    if (gr < Skv) {
      const unsigned short* kp = Kb + (size_t)gr * kv_rowstride + sc;
      k0v = *(const v8s*)kp;  k1v = *(const v8s*)(kp + 8);
    }
    // V: row d=sr of Vt, kv range [base+sc, base+sc+16) -- always in kvpad bounds
    const unsigned short* vp = Vtb + (size_t)sr * kvpad + base + sc;
    v8s w0 = *(const v8s*)vp;
    v8s w1 = *(const v8s*)(vp + 8);
    __syncthreads();            // prev chunk's reads done
    *(v8s*)&lK[sr][sc]     = k0v;
    *(v8s*)&lK[sr][sc + 8] = k1v;
    {  // lV row stride 72 shorts: 16B-unaligned for odd rows -> 8B stores
      v4s a0 = {w0[0], w0[1], w0[2], w0[3]};
      v4s a1 = {w0[4], w0[5], w0[6], w0[7]};
      v4s a2 = {w1[0], w1[1], w1[2], w1[3]};
      v4s a3 = {w1[4], w1[5], w1[6], w1[7]};
      *(v4s*)&lV[sr][sc]      = a0;
      *(v4s*)&lV[sr][sc + 4]  = a1;
      *(v4s*)&lV[sr][sc + 8]  = a2;
      *(v4s*)&lV[sr][sc + 12] = a3;
    }
    __syncthreads();

    // S = Q K^T for 4 kv sub-tiles of 16
    float s[4][4];
#pragma unroll
    for (int t = 0; t < 4; t++) {
      v8s kf0 = *(const v8s*)&lK[t * 16 + l15][quad * 8];
      v8s kf1 = *(const v8s*)&lK[t * 16 + l15][32 + quad * 8];
      v4f sacc = vzero;
      sacc = __builtin_amdgcn_mfma_f32_16x16x32_bf16(qf0, kf0, sacc, 0, 0, 0);
      sacc = __builtin_amdgcn_mfma_f32_16x16x32_bf16(qf1, kf1, sacc, 0, 0, 0);
      int kvpos = base + t * 16 + l15;     // C-layout col = lane&15
      bool ok = kvpos < Skv;
#pragma unroll
      for (int r = 0; r < 4; r++) s[t][r] = ok ? sacc[r] * scale : -1e30f;
    }

    // online softmax per row (row r lives in the 16 lanes of this quad)
#pragma unroll
    for (int r = 0; r < 4; r++) {
      float mx = fmaxf(fmaxf(s[0][r], s[1][r]), fmaxf(s[2][r], s[3][r]));
#pragma unroll
      for (int d = 1; d < 16; d <<= 1) mx = fmaxf(mx, __shfl_xor(mx, d));
      float mnew = fmaxf(m_r[r], mx);
      float alpha = __expf(m_r[r] - mnew);
      float sm = 0.f;
#pragma unroll
      for (int t = 0; t < 4; t++) { s[t][r] = __expf(s[t][r] - mnew); sm += s[t][r]; }
#pragma unroll
      for (int d = 1; d < 16; d <<= 1) sm += __shfl_xor(sm, d);
      l_r[r] = l_r[r] * alpha + sm;
      m_r[r] = mnew;
#pragma unroll
      for (int t = 0; t < 4; t++) o_acc[t][r] *= alpha;
    }

    // P: C-layout -> per-wave LDS -> A-layout (no barrier: same wave only)
#pragma unroll
    for (int t = 0; t < 4; t++)
#pragma unroll
      for (int r = 0; r < 4; r++)
        lP[wave][quad * 4 + r][t * 16 + l15] = f2bf(s[t][r]);
    v8s pf0 = *(const v8s*)&lP[wave][l15][quad * 8];
    v8s pf1 = *(const v8s*)&lP[wave][l15][32 + quad * 8];
#pragma unroll
    for (int t = 0; t < 4; t++) {
      v8s vf0 = *(const v8s*)&lV[t * 16 + l15][quad * 8];
      v8s vf1 = *(const v8s*)&lV[t * 16 + l15][32 + quad * 8];
      o_acc[t] = __builtin_amdgcn_mfma_f32_16x16x32_bf16(pf0, vf0, o_acc[t], 0, 0, 0);
      o_acc[t] = __builtin_amdgcn_mfma_f32_16x16x32_bf16(pf1, vf1, o_acc[t], 0, 0, 0);
    }
  }

  // epilogue: O /= l, write bf16 head-merged
  int orow0 = b * q_batch_rows + qt * 64 + wave * 16;
#pragma unroll
  for (int t = 0; t < 4; t++) {
#pragma unroll
    for (int r = 0; r < 4; r++) {
      float v = o_acc[t][r] / l_r[r];
      O[(size_t)(orow0 + quad * 4 + r) * o_rowstride + h * 64 + t * 16 + l15] = f2bf(v);
    }
  }
}

// ---------------------------------------------------------------------------
// Fused residual + LayerNorm over D=1024. 256 threads, 4 cols/thread.
// delta2 nullable (split-K partial sum).
// ---------------------------------------------------------------------------
__global__ __launch_bounds__(256)
void ln_kernel(const float* base, const float* __restrict__ delta,
               const float* __restrict__ delta2,
               const float* __restrict__ g, const float* __restrict__ bb,
               float* outf, unsigned short* __restrict__ outb) {
  __shared__ float red[8];
  int row = blockIdx.x;
  int tid = threadIdx.x;
  float4 vb = ((const float4*)(base  + (size_t)row * 1024))[tid];
  float4 vd = ((const float4*)(delta + (size_t)row * 1024))[tid];
  float v0 = vb.x + vd.x, v1 = vb.y + vd.y, v2 = vb.z + vd.z, v3 = vb.w + vd.w;
  if (delta2) {
    float4 v2d = ((const float4*)(delta2 + (size_t)row * 1024))[tid];
    v0 += v2d.x; v1 += v2d.y; v2 += v2d.z; v3 += v2d.w;
  }
  float s = v0 + v1 + v2 + v3;
  float q = v0 * v0 + v1 * v1 + v2 * v2 + v3 * v3;
#pragma unroll
  for (int d = 1; d < 64; d <<= 1) { s += __shfl_xor(s, d); q += __shfl_xor(q, d); }
  int wave = tid >> 6, lane = tid & 63;
  if (lane == 0) { red[wave] = s; red[4 + wave] = q; }
  __syncthreads();
  s = red[0] + red[1] + red[2] + red[3];
  q = red[4] + red[5] + red[6] + red[7];
  float mean = s * (1.f / 1024.f);
  float var  = q * (1.f / 1024.f) - mean * mean;
  float rstd = rsqrtf(var + 1e-5f);
  float4 gg  = ((const float4*)g)[tid];
  float4 bv  = ((const float4*)bb)[tid];
  float o0 = (v0 - mean) * rstd * gg.x + bv.x;
  float o1 = (v1 - mean) * rstd * gg.y + bv.y;
  float o2 = (v2 - mean) * rstd * gg.z + bv.z;
  float o3 = (v3 - mean) * rstd * gg.w + bv.w;
  if (outf) {
    float4 o; o.x = o0; o.y = o1; o.z = o2; o.w = o3;
    ((float4*)(outf + (size_t)row * 1024))[tid] = o;
  }
  if (outb) {
    ushort4 u; u.x = f2bf(o0); u.y = f2bf(o1); u.z = f2bf(o2); u.w = f2bf(o3);
    ((ushort4*)(outb + (size_t)row * 1024))[tid] = u;
  }
}

// ---------------------------------------------------------------------------
// Launch
// ---------------------------------------------------------------------------
extern "C" void kernel_launch(void* const* d_in, const int* in_sizes, int n_in,
                              void* d_out, int out_size, void* d_ws, size_t ws_size,
                              hipStream_t stream) {
  const float* x     = (const float*)d_in[0];
  const float* y     = (const float*)d_in[1];
  const float* w_qkv = (const float*)d_in[2];
  const float* b_qkv = (const float*)d_in[3];
  const float* w_so  = (const float*)d_in[4];
  const float* b_so  = (const float*)d_in[5];
  const float* w_q   = (const float*)d_in[6];
  const float* b_q   = (const float*)d_in[7];
  const float* w_k   = (const float*)d_in[8];
  const float* b_k   = (const float*)d_in[9];
  const float* w_v   = (const float*)d_in[10];
  const float* b_v   = (const float*)d_in[11];
  const float* w_co  = (const float*)d_in[12];
  const float* b_co  = (const float*)d_in[13];
  const float* w1    = (const float*)d_in[14];
  const float* b1    = (const float*)d_in[15];
  const float* w2    = (const float*)d_in[16];
  const float* b2    = (const float*)d_in[17];
  const float* w3    = (const float*)d_in[18];
  const float* b3    = (const float*)d_in[19];
  const float* ln_g  = (const float*)d_in[20];
  const float* ln_b  = (const float*)d_in[21];

  char* ws = (char*)d_ws;
  auto US = [&](size_t off) { return (unsigned short*)(ws + off); };
  auto FP = [&](size_t off) { return (float*)(ws + off); };

  // ws layout (bytes). Total ~168 MB (unchanged; new buffers overlay dead spans).
  constexpr size_t o_wqkv = 0;                                 // [3072,1024] bf16
  constexpr size_t o_wso  = o_wqkv + 3072ull * 1024 * 2;       // [1024,1024]
  constexpr size_t o_wq   = o_wso  + 1024ull * 1024 * 2;
  constexpr size_t o_wk   = o_wq   + 1024ull * 1024 * 2;       // [1024,768]
  constexpr size_t o_wv   = o_wk   + 1024ull * 768 * 2;
  constexpr size_t o_wco  = o_wv   + 1024ull * 768 * 2;
  constexpr size_t o_w1   = o_wco  + 1024ull * 1024 * 2;       // [4096,1024]
  constexpr size_t o_w2   = o_w1   + 4096ull * 1024 * 2;       // [4096,4096]
  constexpr size_t o_w3   = o_w2   + 4096ull * 4096 * 2;       // [1024,4096]
  constexpr size_t o_xf   = o_w3   + 1024ull * 4096 * 2;       // x fp32 [4096,1024]
  constexpr size_t o_xbf  = o_xf   + 4096ull * 1024 * 4;       // x bf16
  constexpr size_t o_ybf  = o_xbf  + 4096ull * 1024 * 2;       // y bf16 [308,768]
  constexpr size_t o_dlt  = o_ybf  + 308ull * 768 * 2;         // delta fp32 [4096,1024]
  constexpr size_t o_R1   = o_dlt  + 4096ull * 1024 * 4;       // qkv bf16 [4096,3072] (24 MB)
  constexpr size_t o_attn = o_R1   + 4096ull * 3072 * 2;       // attn out bf16 [4096,1024]
  constexpr size_t o_R2   = o_attn + 4096ull * 1024 * 2;       // h2 bf16 [4096,4096] (32 MB)
  // overlays (liveness-checked):
  constexpr size_t o_qc  = o_R1;                               // cross: qc [4096,1024]
  constexpr size_t o_kc  = o_R1 + 4096ull * 1024 * 2;          // kc [308,1024]
  constexpr size_t o_vc  = o_kc + 308ull * 1024 * 2;           // vc [308,1024]
  constexpr size_t o_h1  = o_R1;                               // FFN h1 [4096,4096]... spans R1+attn
  constexpr size_t o_h2  = o_R2;
  constexpr size_t o_dlt2 = o_R1;                              // split-K partial (16 MB, dead-R1 moments)
  constexpr size_t o_vtS = o_R2;                               // self Vt [4,16,64,1024] bf16 (8 MB, pre-FFN)
  constexpr size_t o_vtC = o_R2 + 4ull * 16 * 64 * 1024 * 2;   // cross Vt [4,16,64,128] (1 MB)

  dim3 tb(32, 8);
  // weight transpose-converts: in [K,N] fp32 -> out [N,K] bf16, grid (N/32,K/32)
  cvt_transpose<<<dim3(96, 32),  tb, 0, stream>>>(w_qkv, US(o_wqkv), 1024, 3072);
  cvt_transpose<<<dim3(32, 32),  tb, 0, stream>>>(w_so,  US(o_wso),  1024, 1024);
  cvt_transpose<<<dim3(32, 32),  tb, 0, stream>>>(w_q,   US(o_wq),   1024, 1024);
  cvt_transpose<<<dim3(32, 24),  tb, 0, stream>>>(w_k,   US(o_wk),   768,  1024);
  cvt_transpose<<<dim3(32, 24),  tb, 0, stream>>>(w_v,   US(o_wv),   768,  1024);
  cvt_transpose<<<dim3(32, 32),  tb, 0, stream>>>(w_co,  US(o_wco),  1024, 1024);
  cvt_transpose<<<dim3(128, 32), tb, 0, stream>>>(w1,    US(o_w1),   1024, 4096);
  cvt_transpose<<<dim3(128, 128),tb, 0, stream>>>(w2,    US(o_w2),   4096, 4096);
  cvt_transpose<<<dim3(32, 128), tb, 0, stream>>>(w3,    US(o_w3),   4096, 1024);

  cvt_f32_bf16<<<4096, 256, 0, stream>>>(x, US(o_xbf), 4096 * 1024 / 4);
  cvt_f32_bf16<<<231, 256, 0, stream>>>(y, US(o_ybf), 4 * 77 * 768 / 4);

  // --- self attention ---
  gemm_bf16<false, false, true><<<dim3(24, 32, 1), 256, 0, stream>>>(
      US(o_xbf), US(o_wqkv), b_qkv, nullptr, nullptr, US(o_R1), 4096, 3072, 1024, 1024);
  transpose_v<<<dim3(16, 16, 4), 256, 0, stream>>>(
      US(o_R1) + 2048, US(o_vtS), 3072, 1024, 1024, 1024);
  attn_kernel<<<dim3(16, 16, 4), 256, 0, stream>>>(
      US(o_R1), US(o_R1) + 1024, US(o_vtS), US(o_attn),
      3072, 3072, 1024, 1024, 1024, 1024, 1024, 0.125f);
  gemm_bf16<false, true, false><<<dim3(8, 32, 2), 256, 0, stream>>>(   // split-K
      US(o_attn), US(o_wso), b_so, FP(o_dlt), FP(o_dlt2), nullptr, 4096, 1024, 512, 1024);
  ln_kernel<<<4096, 256, 0, stream>>>(x, FP(o_dlt), FP(o_dlt2), ln_g, ln_b,
                                      FP(o_xf), US(o_xbf));

  // --- cross attention ---
  gemm_bf16<false, false, true><<<dim3(8, 32, 1), 256, 0, stream>>>(
      US(o_xbf), US(o_wq), b_q, nullptr, nullptr, US(o_qc), 4096, 1024, 1024, 1024);
  gemm_bf16<false, false, true><<<dim3(8, 3, 1), 256, 0, stream>>>(
      US(o_ybf), US(o_wk), b_k, nullptr, nullptr, US(o_kc), 308, 1024, 768, 768);
  gemm_bf16<false, false, true><<<dim3(8, 3, 1), 256, 0, stream>>>(
      US(o_ybf), US(o_wv), b_v, nullptr, nullptr, US(o_vc), 308, 1024, 768, 768);
  transpose_v<<<dim3(2, 16, 4), 256, 0, stream>>>(
      US(o_vc), US(o_vtC), 1024, 77, 77, 128);
  attn_kernel<<<dim3(16, 16, 4), 256, 0, stream>>>(
      US(o_qc), US(o_kc), US(o_vtC), US(o_attn),
      1024, 1024, 1024, 1024, 77, 77, 128, 0.125f);
  gemm_bf16<false, true, false><<<dim3(8, 32, 2), 256, 0, stream>>>(   // split-K
      US(o_attn), US(o_wco), b_co, FP(o_dlt), FP(o_dlt2), nullptr, 4096, 1024, 512, 1024);
  ln_kernel<<<4096, 256, 0, stream>>>(FP(o_xf), FP(o_dlt), FP(o_dlt2), ln_g, ln_b,
                                      FP(o_xf), US(o_xbf));

  // --- FFN ---
  gemm_bf16<true, false, true><<<dim3(32, 32, 1), 256, 0, stream>>>(
      US(o_xbf), US(o_w1), b1, nullptr, nullptr, US(o_h1), 4096, 4096, 1024, 1024);
  gemm_bf16<true, false, true><<<dim3(32, 32, 1), 256, 0, stream>>>(
      US(o_h1), US(o_w2), b2, nullptr, nullptr, US(o_h2), 4096, 4096, 4096, 4096);
  gemm_bf16<false, true, false><<<dim3(8, 32, 2), 256, 0, stream>>>(   // split-K
      US(o_h2), US(o_w3), b3, FP(o_dlt), FP(o_dlt2), nullptr, 4096, 1024, 2048, 4096);
  ln_kernel<<<4096, 256, 0, stream>>>(FP(o_xf), FP(o_dlt), FP(o_dlt2), ln_g, ln_b,
                                      (float*)d_out, nullptr);
}